// Round 14
// baseline (218.385 us; speedup 1.0000x reference)
//
#include <hip/hip_runtime.h>
#include <hip/hip_bf16.h>

// Problem constants
#define D    1024
#define LD   64
#define NTR  8192
#define NT   8192
#define DY   128

#define SHIFT 40.0f
#define NCHUNK 8
#define CHUNK (NTR / NCHUNK)   // 1024 train rows per chunk, 32 tiles of 32

typedef __attribute__((ext_vector_type(8))) short bf16x8;      // generic 8x16-bit
typedef __attribute__((ext_vector_type(8))) _Float16 half8;    // fp16 MFMA operand
typedef __attribute__((ext_vector_type(4))) short short4_;
typedef __attribute__((ext_vector_type(4))) float f4;

static __device__ __forceinline__ short f2bf(float f) {
    __hip_bfloat16 h = __float2bfloat16(f);
    short s; __builtin_memcpy(&s, &h, 2); return s;
}
static __device__ __forceinline__ float bf2f(short s) {
    __hip_bfloat16 h; __builtin_memcpy(&h, &s, 2); return __bfloat162float(h);
}
static __device__ __forceinline__ short f2h(float f) {
    _Float16 h = (_Float16)f;
    short s; __builtin_memcpy(&s, &h, 2); return s;
}
static __device__ __forceinline__ float h2f(short s) {
    _Float16 h; __builtin_memcpy(&h, &s, 2); return (float)h;
}

// async global->LDS DMA, 16 B per lane: LDS dest = wave-uniform base + lane*16
static __device__ __forceinline__ void gload_lds16(const void* g, void* l) {
    __builtin_amdgcn_global_load_lds(
        (const __attribute__((address_space(1))) unsigned int*)g,
        (__attribute__((address_space(3))) unsigned int*)l,
        16, 0, 0);
}

// ---------------------------------------------------------------------------
// K1 (fused prep+proj, 1280 blocks, NO dependencies between roles):
//   blocks    0..1023 : projection (0..511 test -> qt fp16 hi/lo,
//                       512..1023 train -> ktr fp16 swizzled tiles + muAp slot)
//   blocks 1024..1279 : ytr[NTR][DY] f32 -> V tiles [tile32][dy][32] bf16,
//                       16B chunks swizzled: pos = ((t>>3)&3) ^ (dy&3)
// Projection math: full-precision 6-MFMA split (x hi/lo AND A hi/lo, bf16) —
// R12-verified (k error ~4e-6 rel).  Only the OUTPUT encoding is fp16.
// ---------------------------------------------------------------------------
__global__ __launch_bounds__(256) void proj_prep(const float* __restrict__ xt,
                                                 const float* __restrict__ xtr,
                                                 const float* __restrict__ A,
                                                 const float* __restrict__ ytr,
                                                 short* __restrict__ qt_hi,
                                                 short* __restrict__ qt_lo,
                                                 short* __restrict__ ktr,
                                                 float* __restrict__ muAp,
                                                 short* __restrict__ vtile) {
    __shared__ __align__(16) float smem[4224];   // 16.5 KB, aliased per role

    int tid = threadIdx.x;
    int b = blockIdx.x;

    if (b >= 1024) {
        // ---- ytr transpose -> swizzled V tiles (bf16) ----
        float* tile = smem;                      // [64][66]
        int bz = b - 1024;
        int t0 = (bz & 127) * 64;
        int d0 = (bz >> 7) * 64;
        int c = tid & 63;
        int r4 = tid >> 6;
        #pragma unroll
        for (int i = 0; i < 16; ++i) {
            int r = i * 4 + r4;
            tile[r * 66 + c] = ytr[(long)(t0 + r) * DY + d0 + c];
        }
        __syncthreads();
        #pragma unroll
        for (int i = 0; i < 16; ++i) {
            int r = i * 4 + r4;       // dy local
            int t = t0 + c;
            int dy = d0 + r;
            long idx = (long)(t >> 5) * 4096 + (long)dy * 32
                     + ((((t >> 3) & 3) ^ (dy & 3)) << 3) + (t & 7);
            vtile[idx] = f2bf(tile[c * 66 + r]);
        }
        return;
    }

    // ---- projection ----
    float (*xbuf)[2][1024] = (float (*)[2][1024])smem;   // [dbuf][slice][16x64]

    int wave = tid >> 6;          // = ct (column tile) AND staging row group
    int lane = tid & 63;
    int quad = lane >> 4;
    int l16 = lane & 15;

    bool is_test = b < (NT / 16);
    int row0 = (is_test ? b : b - NT / 16) * 16;
    const float* x = is_test ? xt : xtr;

    // staging: lane covers local row lr = wave*4 + (lane>>4),
    // stored 16B-pos p = lane&15, global chunk c = p ^ (lr&7)
    int lr = wave * 4 + (lane >> 4);
    int cg = (lane & 15) ^ (lr & 7);
    const float* xsrc = x + (long)(row0 + lr) * D + cg * 4;

    int col = wave * 16 + l16;
    const float* Acol = A + col;

    f4 acc = (f4){0.f, 0.f, 0.f, 0.f};

    // fragment chunk positions within a 64-float slice
    int pr0 = ((quad * 2) ^ (l16 & 7)) * 4;
    int pr1 = (((quad * 2) | 1) ^ (l16 & 7)) * 4;

    // stage step 0 (both slices) into buf 0
    gload_lds16(xsrc, &xbuf[0][0][wave * 256]);
    gload_lds16(xsrc + 64, &xbuf[0][1][wave * 256]);
    __syncthreads();

    #pragma unroll 1
    for (int s = 0; s < 8; ++s) {
        int cur = s & 1;
        if (s < 7) {
            const float* nsrc = xsrc + (s + 1) * 128;
            gload_lds16(nsrc, &xbuf[cur ^ 1][0][wave * 256]);
            gload_lds16(nsrc + 64, &xbuf[cur ^ 1][1][wave * 256]);
        }

        #pragma unroll
        for (int s2 = 0; s2 < 2; ++s2) {
            int k0 = s * 128 + s2 * 64;

            // B-fragments inline from A, bf16 hi/lo (col-major, L2-hot)
            bf16x8 bh0, bh1, bl0, bl1;
            #pragma unroll
            for (int j = 0; j < 8; ++j) {
                float a0 = Acol[(long)(k0 + quad * 8 + j) * LD];
                float a1 = Acol[(long)(k0 + 32 + quad * 8 + j) * LD];
                short h0 = f2bf(a0);
                short h1 = f2bf(a1);
                bh0[j] = h0; bl0[j] = f2bf(a0 - bf2f(h0));
                bh1[j] = h1; bl1[j] = f2bf(a1 - bf2f(h1));
            }

            const float* xrow = &xbuf[cur][s2][l16 * 64];
            bf16x8 ah[2], al[2];
            #pragma unroll
            for (int h = 0; h < 2; ++h) {
                f4 v0 = *(const f4*)(xrow + h * 32 + pr0);
                f4 v1 = *(const f4*)(xrow + h * 32 + pr1);
                #pragma unroll
                for (int e = 0; e < 4; ++e) {
                    short hi0 = f2bf(v0[e]);
                    short hi1 = f2bf(v1[e]);
                    ah[h][e]     = hi0;
                    ah[h][e + 4] = hi1;
                    al[h][e]     = f2bf(v0[e] - bf2f(hi0));
                    al[h][e + 4] = f2bf(v1[e] - bf2f(hi1));
                }
            }
            acc = __builtin_amdgcn_mfma_f32_16x16x32_bf16(ah[0], bh0, acc, 0, 0, 0);
            acc = __builtin_amdgcn_mfma_f32_16x16x32_bf16(al[0], bh0, acc, 0, 0, 0);
            acc = __builtin_amdgcn_mfma_f32_16x16x32_bf16(ah[0], bl0, acc, 0, 0, 0);
            acc = __builtin_amdgcn_mfma_f32_16x16x32_bf16(ah[1], bh1, acc, 0, 0, 0);
            acc = __builtin_amdgcn_mfma_f32_16x16x32_bf16(al[1], bh1, acc, 0, 0, 0);
            acc = __builtin_amdgcn_mfma_f32_16x16x32_bf16(ah[1], bl1, acc, 0, 0, 0);
        }
        __syncthreads();
    }

    // D layout: row = quad*4+r (x-row), col = wave*16+l16.  Outputs fp16.
    #pragma unroll
    for (int r = 0; r < 4; ++r) {
        int grow = row0 + quad * 4 + r;
        float qv = acc[r];
        if (is_test) {
            short hi = f2h(qv);
            qt_hi[(long)grow * LD + col] = hi;
            qt_lo[(long)grow * LD + col] = f2h(qv - h2f(hi));
        } else {
            int tl = grow & 31;
            long idx = (long)(grow >> 5) * 2048 + tl * 64
                     + ((((col >> 3) ^ (tl & 7))) << 3) + (col & 7);
            ktr[idx] = f2h(qv);
        }
    }

    // muA partial (train only): per-block slot, NO atomics / NO zero-init
    if (!is_test) {
        float s = acc[0] + acc[1] + acc[2] + acc[3];
        s += __shfl_xor(s, 16);
        s += __shfl_xor(s, 32);
        if (quad == 0) muAp[(long)(b - NT / 16) * 64 + col] = s;
    }
}

// ---------------------------------------------------------------------------
// K2: cc[t] = muA . k_f16[t] + SHIFT  (k_f16 = the fp16 K flash uses).
// 32 blocks x 256, one t per thread; each block reduces muAp first.
// ---------------------------------------------------------------------------
__global__ __launch_bounds__(256) void c_kernel(const short* __restrict__ ktr,
                                                const float* __restrict__ muAp,
                                                float* __restrict__ cc) {
    __shared__ float red[4][64];
    __shared__ __align__(16) float muAs[64];
    int l = threadIdx.x & 63;
    int g = threadIdx.x >> 6;
    float ms = 0.f;
    #pragma unroll 8
    for (int p = g; p < 512; p += 4) ms += muAp[(long)p * 64 + l];
    red[g][l] = ms;
    __syncthreads();
    if (threadIdx.x < 64)
        muAs[l] = (red[0][l] + red[1][l] + red[2][l] + red[3][l]) *
                  (1.0f / (float)NTR);
    __syncthreads();

    int t = blockIdx.x * 256 + threadIdx.x;
    int tl = t & 31;
    long rb = (long)(t >> 5) * 2048 + tl * 64;
    float s = SHIFT;
    #pragma unroll
    for (int c = 0; c < 8; ++c) {
        int pos = (c ^ (tl & 7)) << 3;
        bf16x8 h8 = *(const bf16x8*)&ktr[rb + pos];   // fp16 bits
        f4 m0 = *(const f4*)&muAs[c * 8];
        f4 m1 = *(const f4*)&muAs[c * 8 + 4];
        #pragma unroll
        for (int j = 0; j < 4; ++j) {
            s += h2f(h8[j]) * m0[j];
            s += h2f(h8[j + 4]) * m1[j];
        }
    }
    cc[t] = s;
}

// ---------------------------------------------------------------------------
// K3: flash attention.  Grid 512 = 64 Q-tiles(128 rows) x 8 K-chunks(1024).
// q=32/wave.  K staged as SINGLE fp16 (4 KB/tile) + V bf16 via
// global_load_lds (double-buffered, one barrier/iter).
// QK in fp16: s = k_f16 . (q_hi + q_lo), both q parts fp16 in registers —
// logit err ~1.3e-3 std (vs 0.0127 that failed R13).  P/V stay bf16
// (P needs bf16's exponent range: p ~ e^-40).  LDS 34 KB -> 4 blocks/CU.
// ---------------------------------------------------------------------------
__global__ __launch_bounds__(256, 4) void flash_kernel(const short* __restrict__ qt_hi,
                                                       const short* __restrict__ qt_lo,
                                                       const short* __restrict__ ksw,
                                                       const short* __restrict__ vtile,
                                                       const float* __restrict__ cc,
                                                       short* __restrict__ Opart,
                                                       float* __restrict__ Lpart) {
    __shared__ __align__(16) short kbh[2][2048];    //  8 KB  K fp16 tiles
    __shared__ __align__(16) short vbuf[2][4096];   // 16 KB  V bf16 tiles
    __shared__ __align__(16) short ptile[4][1280];  // 10 KB  per-wave P[32][32] pitch 40

    int tid = threadIdx.x;
    int wave = tid >> 6;
    int lane = tid & 63;
    int quad = lane >> 4;
    int l16 = lane & 15;

    int kc = blockIdx.x & 7;              // blockIdx%8 -> XCD-affine chunk
    int qi = blockIdx.x >> 3;
    int q0w = qi * 128 + wave * 32;
    int tile0 = kc * 32;
    int kc0 = kc * CHUNK;

    int soff = wave * 512 + lane * 8;     // staging src offset (shorts)
    int ldso = wave * 512;                // staging LDS base (wave-uniform)

    // Q fragments, fp16 hi/lo (B-operand for S^T)
    half8 qh[2][2], ql[2][2];
    #pragma unroll
    for (int rt = 0; rt < 2; ++rt) {
        const short* qrh = qt_hi + (long)(q0w + rt * 16 + l16) * LD + quad * 8;
        const short* qrl = qt_lo + (long)(q0w + rt * 16 + l16) * LD + quad * 8;
        qh[rt][0] = *(const half8*)qrh;
        qh[rt][1] = *(const half8*)(qrh + 32);
        ql[rt][0] = *(const half8*)qrl;
        ql[rt][1] = *(const half8*)(qrl + 32);
    }

    bf16x8 onef;
    #pragma unroll
    for (int i = 0; i < 8; ++i) onef[i] = (short)0x3F80;   // bf16(1.0)

    f4 Ov[2][8];
    f4 Lv[2];
    #pragma unroll
    for (int rt = 0; rt < 2; ++rt) {
        Lv[rt] = (f4){0.f, 0.f, 0.f, 0.f};
        #pragma unroll
        for (int jt = 0; jt < 8; ++jt) Ov[rt][jt] = (f4){0.f, 0.f, 0.f, 0.f};
    }

    short* myp = &ptile[wave][0];
    const int p0 = ((quad ^ (l16 & 7)) << 3);          // K chunk pos; h2=1 -> ^32
    const int pv = ((quad ^ (l16 & 3)) << 3);          // V chunk pos

    gload_lds16(ksw + (long)tile0 * 2048 + soff, &kbh[0][ldso]);
    gload_lds16(vtile + (long)tile0 * 4096 + soff, &vbuf[0][ldso]);
    gload_lds16(vtile + (long)tile0 * 4096 + 2048 + soff, &vbuf[0][2048 + ldso]);
    __syncthreads();

    #pragma unroll 1
    for (int it = 0; it < 32; ++it) {
        int cur = it & 1;

        f4 cv[2];
        #pragma unroll
        for (int tt = 0; tt < 2; ++tt)
            cv[tt] = *(const f4*)&cc[kc0 + it * 32 + tt * 16 + quad * 4];

        if (it < 31) {
            int nb = cur ^ 1;
            long tb = (long)(tile0 + it + 1);
            gload_lds16(ksw + tb * 2048 + soff, &kbh[nb][ldso]);
            gload_lds16(vtile + tb * 4096 + soff, &vbuf[nb][ldso]);
            gload_lds16(vtile + tb * 4096 + 2048 + soff, &vbuf[nb][2048 + ldso]);
        }

        half8 kh[2][2];                    // [tt][h2], fp16
        #pragma unroll
        for (int tt = 0; tt < 2; ++tt) {
            int rb = (tt * 16 + l16) * 64;
            kh[tt][0] = *(const half8*)&kbh[cur][rb + p0];
            kh[tt][1] = *(const half8*)&kbh[cur][rb + (p0 ^ 32)];
        }

        f4 s[2][2];
        #pragma unroll
        for (int rt = 0; rt < 2; ++rt) {
            #pragma unroll
            for (int tt = 0; tt < 2; ++tt) {
                f4 a = (f4){0.f, 0.f, 0.f, 0.f};
                a = __builtin_amdgcn_mfma_f32_16x16x32_f16(kh[tt][0], qh[rt][0], a, 0, 0, 0);
                a = __builtin_amdgcn_mfma_f32_16x16x32_f16(kh[tt][0], ql[rt][0], a, 0, 0, 0);
                a = __builtin_amdgcn_mfma_f32_16x16x32_f16(kh[tt][1], qh[rt][1], a, 0, 0, 0);
                a = __builtin_amdgcn_mfma_f32_16x16x32_f16(kh[tt][1], ql[rt][1], a, 0, 0, 0);
                s[rt][tt] = a;
            }
        }

        #pragma unroll
        for (int rt = 0; rt < 2; ++rt) {
            #pragma unroll
            for (int tt = 0; tt < 2; ++tt) {
                short4_ p4;
                p4[0] = f2bf(__expf(s[rt][tt][0] - cv[tt][0]));
                p4[1] = f2bf(__expf(s[rt][tt][1] - cv[tt][1]));
                p4[2] = f2bf(__expf(s[rt][tt][2] - cv[tt][2]));
                p4[3] = f2bf(__expf(s[rt][tt][3] - cv[tt][3]));
                *(short4_*)&myp[(rt * 16 + l16) * 40 + tt * 16 + quad * 4] = p4;
            }
        }

        bf16x8 vf[8];
        #pragma unroll
        for (int jt = 0; jt < 8; ++jt)
            vf[jt] = *(const bf16x8*)&vbuf[cur][(jt * 16 + l16) * 32 + pv];
        #pragma unroll
        for (int rt = 0; rt < 2; ++rt) {
            bf16x8 pf = *(const bf16x8*)&myp[(rt * 16 + l16) * 40 + quad * 8];
            #pragma unroll
            for (int jt = 0; jt < 8; ++jt)
                Ov[rt][jt] = __builtin_amdgcn_mfma_f32_16x16x32_bf16(pf, vf[jt], Ov[rt][jt], 0, 0, 0);
            Lv[rt] = __builtin_amdgcn_mfma_f32_16x16x32_bf16(pf, onef, Lv[rt], 0, 0, 0);
        }

        __syncthreads();
    }

    long ob = (long)kc * NT;
    #pragma unroll
    for (int rt = 0; rt < 2; ++rt) {
        #pragma unroll
        for (int jt = 0; jt < 8; ++jt) {
            #pragma unroll
            for (int r = 0; r < 4; ++r)
                Opart[(ob + q0w + rt * 16 + quad * 4 + r) * DY + jt * 16 + l16] =
                    f2bf(Ov[rt][jt][r]);
        }
        if (l16 == 0) {
            #pragma unroll
            for (int r = 0; r < 4; ++r)
                Lpart[ob + q0w + rt * 16 + quad * 4 + r] = Lv[rt][r];
        }
    }
}

// ---------------------------------------------------------------------------
// K4: out[q][dy] = sum_kc Opart[kc][q][dy] / sum_kc Lpart[kc][q]  (bf16 parts)
// ---------------------------------------------------------------------------
__global__ __launch_bounds__(256) void finalize_kernel(const short* __restrict__ Opart,
                                                       const float* __restrict__ Lpart,
                                                       float* __restrict__ out) {
    long i = ((long)blockIdx.x * 256 + threadIdx.x) * 8;
    long row = i >> 7;          // DY = 128
    float L = 0.f;
    f4 a = (f4){0.f, 0.f, 0.f, 0.f};
    f4 b = (f4){0.f, 0.f, 0.f, 0.f};
    #pragma unroll
    for (int kc = 0; kc < NCHUNK; ++kc) {
        L += Lpart[(long)kc * NT + row];
        bf16x8 o = *(const bf16x8*)&Opart[(long)kc * NT * DY + i];
        #pragma unroll
        for (int j = 0; j < 4; ++j) {
            a[j] += bf2f(o[j]);
            b[j] += bf2f(o[j + 4]);
        }
    }
    float linv = 1.0f / L;
    a *= linv; b *= linv;
    *(f4*)&out[i] = a;
    *(f4*)&out[i + 4] = b;
}

// ---------------------------------------------------------------------------
extern "C" void kernel_launch(void* const* d_in, const int* in_sizes, int n_in,
                              void* d_out, int out_size, void* d_ws, size_t ws_size,
                              hipStream_t stream) {
    const float* xtr = (const float*)d_in[0];   // [NTR, D]
    const float* ytr = (const float*)d_in[1];   // [NTR, DY]
    const float* xt  = (const float*)d_in[2];   // [NT, D]
    const float* A   = (const float*)d_in[3];   // [D, LD]
    float* out = (float*)d_out;                 // [NT, DY]

    // workspace carving (no memset needed: muAp slots are fully written)
    char* w = (char*)d_ws;
    float* muAp  = (float*)w; w += (size_t)512 * 64 * 4;          // 128 KB
    float* cc    = (float*)w; w += (size_t)NTR * 4;               // 32 KB
    float* Lpart = (float*)w; w += (size_t)NCHUNK * NT * 4;       // 256 KB
    short* Opart = (short*)w; w += (size_t)NCHUNK * NT * DY * 2;  // 16 MB (bf16)
    short* qt_hi  = (short*)w; w += (size_t)NT * LD * 2;          // 1 MB each (fp16)
    short* qt_lo  = (short*)w; w += (size_t)NT * LD * 2;
    short* ksw    = (short*)w; w += (size_t)NTR * LD * 2;         // fp16 swizzled tiles
    short* vtile  = (short*)w; w += (size_t)DY * NTR * 2;         // 2 MB bf16 swizzled
    (void)ws_size; (void)in_sizes; (void)n_in; (void)out_size;

    proj_prep<<<1280, 256, 0, stream>>>(xt, xtr, A, ytr,
                                        qt_hi, qt_lo, ksw, muAp, vtile);
    c_kernel<<<32, 256, 0, stream>>>(ksw, muAp, cc);
    flash_kernel<<<512, 256, 0, stream>>>(qt_hi, qt_lo, ksw, vtile, cc,
                                          Opart, Lpart);
    finalize_kernel<<<(NT * DY) / (256 * 8), 256, 0, stream>>>(Opart, Lpart, out);
}

// Round 15
// 167.396 us; speedup vs baseline: 1.3046x; 1.3046x over previous
//
#include <hip/hip_runtime.h>
#include <hip/hip_bf16.h>

// Problem constants
#define D    1024
#define LD   64
#define NTR  8192
#define NT   8192
#define DY   128

#define SHIFT 40.0f
#define NCHUNK 8
#define CHUNK (NTR / NCHUNK)   // 1024 train rows per chunk, 32 tiles of 32

typedef __attribute__((ext_vector_type(8))) short bf16x8;      // generic 8x16-bit
typedef __attribute__((ext_vector_type(8))) _Float16 half8;    // fp16 MFMA operand
typedef __attribute__((ext_vector_type(4))) short short4_;
typedef __attribute__((ext_vector_type(4))) float f4;

static __device__ __forceinline__ short f2bf(float f) {
    __hip_bfloat16 h = __float2bfloat16(f);
    short s; __builtin_memcpy(&s, &h, 2); return s;
}
static __device__ __forceinline__ float bf2f(short s) {
    __hip_bfloat16 h; __builtin_memcpy(&h, &s, 2); return __bfloat162float(h);
}
static __device__ __forceinline__ short f2h(float f) {
    _Float16 h = (_Float16)f;
    short s; __builtin_memcpy(&s, &h, 2); return s;
}
static __device__ __forceinline__ float h2f(short s) {
    _Float16 h; __builtin_memcpy(&h, &s, 2); return (float)h;
}

// async global->LDS DMA, 16 B per lane: LDS dest = wave-uniform base + lane*16
static __device__ __forceinline__ void gload_lds16(const void* g, void* l) {
    __builtin_amdgcn_global_load_lds(
        (const __attribute__((address_space(1))) unsigned int*)g,
        (__attribute__((address_space(3))) unsigned int*)l,
        16, 0, 0);
}

// ---------------------------------------------------------------------------
// K1 (fused prep+proj, 1280 blocks, NO dependencies between roles):
//   blocks    0..1023 : projection (0..511 test -> qt fp16 hi/lo,
//                       512..1023 train -> ktr fp16 swizzled tiles + muAp slot)
//   blocks 1024..1279 : ytr[NTR][DY] f32 -> V tiles [tile32][dy][32] bf16,
//                       16B chunks swizzled: pos = ((t>>3)&3) ^ (dy&3)
// Projection math: full-precision 6-MFMA split (x hi/lo AND A hi/lo, bf16) —
// R12-verified (k error ~4e-6 rel).  Only the OUTPUT encoding is fp16.
// ---------------------------------------------------------------------------
__global__ __launch_bounds__(256) void proj_prep(const float* __restrict__ xt,
                                                 const float* __restrict__ xtr,
                                                 const float* __restrict__ A,
                                                 const float* __restrict__ ytr,
                                                 short* __restrict__ qt_hi,
                                                 short* __restrict__ qt_lo,
                                                 short* __restrict__ ktr,
                                                 float* __restrict__ muAp,
                                                 short* __restrict__ vtile) {
    __shared__ __align__(16) float smem[4224];   // 16.5 KB, aliased per role

    int tid = threadIdx.x;
    int b = blockIdx.x;

    if (b >= 1024) {
        // ---- ytr transpose -> swizzled V tiles (bf16) ----
        float* tile = smem;                      // [64][66]
        int bz = b - 1024;
        int t0 = (bz & 127) * 64;
        int d0 = (bz >> 7) * 64;
        int c = tid & 63;
        int r4 = tid >> 6;
        #pragma unroll
        for (int i = 0; i < 16; ++i) {
            int r = i * 4 + r4;
            tile[r * 66 + c] = ytr[(long)(t0 + r) * DY + d0 + c];
        }
        __syncthreads();
        #pragma unroll
        for (int i = 0; i < 16; ++i) {
            int r = i * 4 + r4;       // dy local
            int t = t0 + c;
            int dy = d0 + r;
            long idx = (long)(t >> 5) * 4096 + (long)dy * 32
                     + ((((t >> 3) & 3) ^ (dy & 3)) << 3) + (t & 7);
            vtile[idx] = f2bf(tile[c * 66 + r]);
        }
        return;
    }

    // ---- projection ----
    float (*xbuf)[2][1024] = (float (*)[2][1024])smem;   // [dbuf][slice][16x64]

    int wave = tid >> 6;          // = ct (column tile) AND staging row group
    int lane = tid & 63;
    int quad = lane >> 4;
    int l16 = lane & 15;

    bool is_test = b < (NT / 16);
    int row0 = (is_test ? b : b - NT / 16) * 16;
    const float* x = is_test ? xt : xtr;

    // staging: lane covers local row lr = wave*4 + (lane>>4),
    // stored 16B-pos p = lane&15, global chunk c = p ^ (lr&7)
    int lr = wave * 4 + (lane >> 4);
    int cg = (lane & 15) ^ (lr & 7);
    const float* xsrc = x + (long)(row0 + lr) * D + cg * 4;

    int col = wave * 16 + l16;
    const float* Acol = A + col;

    f4 acc = (f4){0.f, 0.f, 0.f, 0.f};

    // fragment chunk positions within a 64-float slice
    int pr0 = ((quad * 2) ^ (l16 & 7)) * 4;
    int pr1 = (((quad * 2) | 1) ^ (l16 & 7)) * 4;

    // stage step 0 (both slices) into buf 0
    gload_lds16(xsrc, &xbuf[0][0][wave * 256]);
    gload_lds16(xsrc + 64, &xbuf[0][1][wave * 256]);
    __syncthreads();

    #pragma unroll 1
    for (int s = 0; s < 8; ++s) {
        int cur = s & 1;
        if (s < 7) {
            const float* nsrc = xsrc + (s + 1) * 128;
            gload_lds16(nsrc, &xbuf[cur ^ 1][0][wave * 256]);
            gload_lds16(nsrc + 64, &xbuf[cur ^ 1][1][wave * 256]);
        }

        #pragma unroll
        for (int s2 = 0; s2 < 2; ++s2) {
            int k0 = s * 128 + s2 * 64;

            // B-fragments inline from A, bf16 hi/lo (col-major, L2-hot)
            bf16x8 bh0, bh1, bl0, bl1;
            #pragma unroll
            for (int j = 0; j < 8; ++j) {
                float a0 = Acol[(long)(k0 + quad * 8 + j) * LD];
                float a1 = Acol[(long)(k0 + 32 + quad * 8 + j) * LD];
                short h0 = f2bf(a0);
                short h1 = f2bf(a1);
                bh0[j] = h0; bl0[j] = f2bf(a0 - bf2f(h0));
                bh1[j] = h1; bl1[j] = f2bf(a1 - bf2f(h1));
            }

            const float* xrow = &xbuf[cur][s2][l16 * 64];
            bf16x8 ah[2], al[2];
            #pragma unroll
            for (int h = 0; h < 2; ++h) {
                f4 v0 = *(const f4*)(xrow + h * 32 + pr0);
                f4 v1 = *(const f4*)(xrow + h * 32 + pr1);
                #pragma unroll
                for (int e = 0; e < 4; ++e) {
                    short hi0 = f2bf(v0[e]);
                    short hi1 = f2bf(v1[e]);
                    ah[h][e]     = hi0;
                    ah[h][e + 4] = hi1;
                    al[h][e]     = f2bf(v0[e] - bf2f(hi0));
                    al[h][e + 4] = f2bf(v1[e] - bf2f(hi1));
                }
            }
            acc = __builtin_amdgcn_mfma_f32_16x16x32_bf16(ah[0], bh0, acc, 0, 0, 0);
            acc = __builtin_amdgcn_mfma_f32_16x16x32_bf16(al[0], bh0, acc, 0, 0, 0);
            acc = __builtin_amdgcn_mfma_f32_16x16x32_bf16(ah[0], bl0, acc, 0, 0, 0);
            acc = __builtin_amdgcn_mfma_f32_16x16x32_bf16(ah[1], bh1, acc, 0, 0, 0);
            acc = __builtin_amdgcn_mfma_f32_16x16x32_bf16(al[1], bh1, acc, 0, 0, 0);
            acc = __builtin_amdgcn_mfma_f32_16x16x32_bf16(ah[1], bl1, acc, 0, 0, 0);
        }
        __syncthreads();
    }

    // D layout: row = quad*4+r (x-row), col = wave*16+l16.  Outputs fp16.
    #pragma unroll
    for (int r = 0; r < 4; ++r) {
        int grow = row0 + quad * 4 + r;
        float qv = acc[r];
        if (is_test) {
            short hi = f2h(qv);
            qt_hi[(long)grow * LD + col] = hi;
            qt_lo[(long)grow * LD + col] = f2h(qv - h2f(hi));
        } else {
            int tl = grow & 31;
            long idx = (long)(grow >> 5) * 2048 + tl * 64
                     + ((((col >> 3) ^ (tl & 7))) << 3) + (col & 7);
            ktr[idx] = f2h(qv);
        }
    }

    // muA partial (train only): per-block slot, NO atomics / NO zero-init
    if (!is_test) {
        float s = acc[0] + acc[1] + acc[2] + acc[3];
        s += __shfl_xor(s, 16);
        s += __shfl_xor(s, 32);
        if (quad == 0) muAp[(long)(b - NT / 16) * 64 + col] = s;
    }
}

// ---------------------------------------------------------------------------
// K2: cc[t] = muA . k_f16[t] + SHIFT  (k_f16 = the fp16 K flash uses).
// 32 blocks x 256, one t per thread; each block reduces muAp first.
// ---------------------------------------------------------------------------
__global__ __launch_bounds__(256) void c_kernel(const short* __restrict__ ktr,
                                                const float* __restrict__ muAp,
                                                float* __restrict__ cc) {
    __shared__ float red[4][64];
    __shared__ __align__(16) float muAs[64];
    int l = threadIdx.x & 63;
    int g = threadIdx.x >> 6;
    float ms = 0.f;
    #pragma unroll 8
    for (int p = g; p < 512; p += 4) ms += muAp[(long)p * 64 + l];
    red[g][l] = ms;
    __syncthreads();
    if (threadIdx.x < 64)
        muAs[l] = (red[0][l] + red[1][l] + red[2][l] + red[3][l]) *
                  (1.0f / (float)NTR);
    __syncthreads();

    int t = blockIdx.x * 256 + threadIdx.x;
    int tl = t & 31;
    long rb = (long)(t >> 5) * 2048 + tl * 64;
    float s = SHIFT;
    #pragma unroll
    for (int c = 0; c < 8; ++c) {
        int pos = (c ^ (tl & 7)) << 3;
        bf16x8 h8 = *(const bf16x8*)&ktr[rb + pos];   // fp16 bits
        f4 m0 = *(const f4*)&muAs[c * 8];
        f4 m1 = *(const f4*)&muAs[c * 8 + 4];
        #pragma unroll
        for (int j = 0; j < 4; ++j) {
            s += h2f(h8[j]) * m0[j];
            s += h2f(h8[j + 4]) * m1[j];
        }
    }
    cc[t] = s;
}

// ---------------------------------------------------------------------------
// K3: flash attention.  Grid 512 = 64 Q-tiles(128 rows) x 8 K-chunks(1024).
// q=32/wave.  K staged as SINGLE fp16 (4 KB/tile) + V bf16 via
// global_load_lds (double-buffered, one barrier/iter).
// QK in fp16: s = k_f16 . (q_hi + q_lo) — logit err ~1.3e-3 std.
// P/V stay bf16 (P needs bf16's exponent range: p ~ e^-40).
// __launch_bounds__(256,3): unified reg budget 170 — fits ~88 VGPR + 64 AGPR
// WITHOUT spill ((256,4) capped at 128 and spilled to scratch: R14's 99 us).
// ---------------------------------------------------------------------------
__global__ __launch_bounds__(256, 3) void flash_kernel(const short* __restrict__ qt_hi,
                                                       const short* __restrict__ qt_lo,
                                                       const short* __restrict__ ksw,
                                                       const short* __restrict__ vtile,
                                                       const float* __restrict__ cc,
                                                       short* __restrict__ Opart,
                                                       float* __restrict__ Lpart) {
    __shared__ __align__(16) short kbh[2][2048];    //  8 KB  K fp16 tiles
    __shared__ __align__(16) short vbuf[2][4096];   // 16 KB  V bf16 tiles
    __shared__ __align__(16) short ptile[4][1280];  // 10 KB  per-wave P[32][32] pitch 40

    int tid = threadIdx.x;
    int wave = tid >> 6;
    int lane = tid & 63;
    int quad = lane >> 4;
    int l16 = lane & 15;

    int kc = blockIdx.x & 7;              // blockIdx%8 -> XCD-affine chunk
    int qi = blockIdx.x >> 3;
    int q0w = qi * 128 + wave * 32;
    int tile0 = kc * 32;
    int kc0 = kc * CHUNK;

    int soff = wave * 512 + lane * 8;     // staging src offset (shorts)
    int ldso = wave * 512;                // staging LDS base (wave-uniform)

    // Q fragments, fp16 hi/lo (B-operand for S^T)
    half8 qh[2][2], ql[2][2];
    #pragma unroll
    for (int rt = 0; rt < 2; ++rt) {
        const short* qrh = qt_hi + (long)(q0w + rt * 16 + l16) * LD + quad * 8;
        const short* qrl = qt_lo + (long)(q0w + rt * 16 + l16) * LD + quad * 8;
        qh[rt][0] = *(const half8*)qrh;
        qh[rt][1] = *(const half8*)(qrh + 32);
        ql[rt][0] = *(const half8*)qrl;
        ql[rt][1] = *(const half8*)(qrl + 32);
    }

    bf16x8 onef;
    #pragma unroll
    for (int i = 0; i < 8; ++i) onef[i] = (short)0x3F80;   // bf16(1.0)

    f4 Ov[2][8];
    f4 Lv[2];
    #pragma unroll
    for (int rt = 0; rt < 2; ++rt) {
        Lv[rt] = (f4){0.f, 0.f, 0.f, 0.f};
        #pragma unroll
        for (int jt = 0; jt < 8; ++jt) Ov[rt][jt] = (f4){0.f, 0.f, 0.f, 0.f};
    }

    short* myp = &ptile[wave][0];
    const int p0 = ((quad ^ (l16 & 7)) << 3);          // K chunk pos; h2=1 -> ^32
    const int pv = ((quad ^ (l16 & 3)) << 3);          // V chunk pos

    gload_lds16(ksw + (long)tile0 * 2048 + soff, &kbh[0][ldso]);
    gload_lds16(vtile + (long)tile0 * 4096 + soff, &vbuf[0][ldso]);
    gload_lds16(vtile + (long)tile0 * 4096 + 2048 + soff, &vbuf[0][2048 + ldso]);
    __syncthreads();

    #pragma unroll 1
    for (int it = 0; it < 32; ++it) {
        int cur = it & 1;

        f4 cv[2];
        #pragma unroll
        for (int tt = 0; tt < 2; ++tt)
            cv[tt] = *(const f4*)&cc[kc0 + it * 32 + tt * 16 + quad * 4];

        if (it < 31) {
            int nb = cur ^ 1;
            long tb = (long)(tile0 + it + 1);
            gload_lds16(ksw + tb * 2048 + soff, &kbh[nb][ldso]);
            gload_lds16(vtile + tb * 4096 + soff, &vbuf[nb][ldso]);
            gload_lds16(vtile + tb * 4096 + 2048 + soff, &vbuf[nb][2048 + ldso]);
        }

        half8 kh[2][2];                    // [tt][h2], fp16
        #pragma unroll
        for (int tt = 0; tt < 2; ++tt) {
            int rb = (tt * 16 + l16) * 64;
            kh[tt][0] = *(const half8*)&kbh[cur][rb + p0];
            kh[tt][1] = *(const half8*)&kbh[cur][rb + (p0 ^ 32)];
        }

        f4 s[2][2];
        #pragma unroll
        for (int rt = 0; rt < 2; ++rt) {
            #pragma unroll
            for (int tt = 0; tt < 2; ++tt) {
                f4 a = (f4){0.f, 0.f, 0.f, 0.f};
                a = __builtin_amdgcn_mfma_f32_16x16x32_f16(kh[tt][0], qh[rt][0], a, 0, 0, 0);
                a = __builtin_amdgcn_mfma_f32_16x16x32_f16(kh[tt][0], ql[rt][0], a, 0, 0, 0);
                a = __builtin_amdgcn_mfma_f32_16x16x32_f16(kh[tt][1], qh[rt][1], a, 0, 0, 0);
                a = __builtin_amdgcn_mfma_f32_16x16x32_f16(kh[tt][1], ql[rt][1], a, 0, 0, 0);
                s[rt][tt] = a;
            }
        }

        #pragma unroll
        for (int rt = 0; rt < 2; ++rt) {
            #pragma unroll
            for (int tt = 0; tt < 2; ++tt) {
                short4_ p4;
                p4[0] = f2bf(__expf(s[rt][tt][0] - cv[tt][0]));
                p4[1] = f2bf(__expf(s[rt][tt][1] - cv[tt][1]));
                p4[2] = f2bf(__expf(s[rt][tt][2] - cv[tt][2]));
                p4[3] = f2bf(__expf(s[rt][tt][3] - cv[tt][3]));
                *(short4_*)&myp[(rt * 16 + l16) * 40 + tt * 16 + quad * 4] = p4;
            }
        }

        bf16x8 vf[8];
        #pragma unroll
        for (int jt = 0; jt < 8; ++jt)
            vf[jt] = *(const bf16x8*)&vbuf[cur][(jt * 16 + l16) * 32 + pv];
        #pragma unroll
        for (int rt = 0; rt < 2; ++rt) {
            bf16x8 pf = *(const bf16x8*)&myp[(rt * 16 + l16) * 40 + quad * 8];
            #pragma unroll
            for (int jt = 0; jt < 8; ++jt)
                Ov[rt][jt] = __builtin_amdgcn_mfma_f32_16x16x32_bf16(pf, vf[jt], Ov[rt][jt], 0, 0, 0);
            Lv[rt] = __builtin_amdgcn_mfma_f32_16x16x32_bf16(pf, onef, Lv[rt], 0, 0, 0);
        }

        __syncthreads();
    }

    long ob = (long)kc * NT;
    #pragma unroll
    for (int rt = 0; rt < 2; ++rt) {
        #pragma unroll
        for (int jt = 0; jt < 8; ++jt) {
            #pragma unroll
            for (int r = 0; r < 4; ++r)
                Opart[(ob + q0w + rt * 16 + quad * 4 + r) * DY + jt * 16 + l16] =
                    f2bf(Ov[rt][jt][r]);
        }
        if (l16 == 0) {
            #pragma unroll
            for (int r = 0; r < 4; ++r)
                Lpart[ob + q0w + rt * 16 + quad * 4 + r] = Lv[rt][r];
        }
    }
}

// ---------------------------------------------------------------------------
// K4: out[q][dy] = sum_kc Opart[kc][q][dy] / sum_kc Lpart[kc][q]  (bf16 parts)
// ---------------------------------------------------------------------------
__global__ __launch_bounds__(256) void finalize_kernel(const short* __restrict__ Opart,
                                                       const float* __restrict__ Lpart,
                                                       float* __restrict__ out) {
    long i = ((long)blockIdx.x * 256 + threadIdx.x) * 8;
    long row = i >> 7;          // DY = 128
    float L = 0.f;
    f4 a = (f4){0.f, 0.f, 0.f, 0.f};
    f4 b = (f4){0.f, 0.f, 0.f, 0.f};
    #pragma unroll
    for (int kc = 0; kc < NCHUNK; ++kc) {
        L += Lpart[(long)kc * NT + row];
        bf16x8 o = *(const bf16x8*)&Opart[(long)kc * NT * DY + i];
        #pragma unroll
        for (int j = 0; j < 4; ++j) {
            a[j] += bf2f(o[j]);
            b[j] += bf2f(o[j + 4]);
        }
    }
    float linv = 1.0f / L;
    a *= linv; b *= linv;
    *(f4*)&out[i] = a;
    *(f4*)&out[i + 4] = b;
}

// ---------------------------------------------------------------------------
extern "C" void kernel_launch(void* const* d_in, const int* in_sizes, int n_in,
                              void* d_out, int out_size, void* d_ws, size_t ws_size,
                              hipStream_t stream) {
    const float* xtr = (const float*)d_in[0];   // [NTR, D]
    const float* ytr = (const float*)d_in[1];   // [NTR, DY]
    const float* xt  = (const float*)d_in[2];   // [NT, D]
    const float* A   = (const float*)d_in[3];   // [D, LD]
    float* out = (float*)d_out;                 // [NT, DY]

    // workspace carving (no memset needed: muAp slots are fully written)
    char* w = (char*)d_ws;
    float* muAp  = (float*)w; w += (size_t)512 * 64 * 4;          // 128 KB
    float* cc    = (float*)w; w += (size_t)NTR * 4;               // 32 KB
    float* Lpart = (float*)w; w += (size_t)NCHUNK * NT * 4;       // 256 KB
    short* Opart = (short*)w; w += (size_t)NCHUNK * NT * DY * 2;  // 16 MB (bf16)
    short* qt_hi  = (short*)w; w += (size_t)NT * LD * 2;          // 1 MB each (fp16)
    short* qt_lo  = (short*)w; w += (size_t)NT * LD * 2;
    short* ksw    = (short*)w; w += (size_t)NTR * LD * 2;         // fp16 swizzled tiles
    short* vtile  = (short*)w; w += (size_t)DY * NTR * 2;         // 2 MB bf16 swizzled
    (void)ws_size; (void)in_sizes; (void)n_in; (void)out_size;

    proj_prep<<<1280, 256, 0, stream>>>(xt, xtr, A, ytr,
                                        qt_hi, qt_lo, ksw, muAp, vtile);
    c_kernel<<<32, 256, 0, stream>>>(ksw, muAp, cc);
    flash_kernel<<<512, 256, 0, stream>>>(qt_hi, qt_lo, ksw, vtile, cc,
                                          Opart, Lpart);
    finalize_kernel<<<(NT * DY) / (256 * 8), 256, 0, stream>>>(Opart, Lpart, out);
}